// Round 7
// baseline (152.002 us; speedup 1.0000x reference)
//
#include <hip/hip_runtime.h>
#include <cstddef>

#define NN 3072
#define RR 16
#define UNROLL 8
#define OUTER 9
#define BLOCKS 2048
// total quads = NN*NN*4 = 37,748,736 = BLOCKS * 256 * UNROLL * OUTER (exact)

typedef float f32x4 __attribute__((ext_vector_type(4)));

// Prologue: key[i] = (cls not in {24,25,26}) ? batch[i] : -1
__global__ void frd_key_kernel(const int* __restrict__ cls,
                               const int* __restrict__ batch,
                               int* __restrict__ key) {
    int i = blockIdx.x * blockDim.x + threadIdx.x;
    if (i < NN) {
        int c = cls[i];
        bool valid = (c != 24) && (c != 25) && (c != 26);
        key[i] = valid ? batch[i] : -1;
    }
}

// Main: block owns a contiguous 288 KB output region (18432 quads), walked as
// OUTER serial steps of UNROLL independent quads per thread. Each store is a
// 1 KB/wave coalesced NT burst; per-wave contiguous run = 72 KB. Fewer, longer
// lived blocks -> fewer concurrent HBM write frontiers than R3's 18432 blocks.
__global__ __launch_bounds__(256)
void frd_main_kernel(const float* __restrict__ z1,
                     const float* __restrict__ z2,
                     const float* __restrict__ seg,
                     const int* __restrict__ key,
                     float* __restrict__ out) {
    const int blockBase = blockIdx.x * (256 * UNROLL * OUTER);
    const float d0 = ((threadIdx.x & 3) == 0) ? 1.0f : 0.0f;  // one_hot(0,R) head

#pragma unroll 1
    for (int t = 0; t < OUTER; ++t) {
        const int base = blockBase + t * (256 * UNROLL) + threadIdx.x;
#pragma unroll
        for (int k = 0; k < UNROLL; ++k) {
            const int idx = base + k * 256;
            const int pair = idx >> 2;
            const int q = idx & 3;
            const int i = pair / NN;          // magic-mul by compiler
            const int j = pair - i * NN;

            // seg index == i*N + j == pair; read-once stream -> NT load
            const float s = __builtin_nontemporal_load(seg + pair);
            const int ki = key[i];            // cache-resident
            const int kj = key[j];
            // seg_eff = seg + eye; pair iff seg_eff == 0, keys match, valid
            const float seg_eff = s + ((i == j) ? 1.0f : 0.0f);
            const bool is_pair = (ki == kj) && (ki >= 0) && (seg_eff == 0.0f);

            // Unconditional loads — z1/z2 are 192 KB each, cache-resident.
            const float4 a = *reinterpret_cast<const float4*>(z1 + i * RR + q * 4);
            const float4 b = *reinterpret_cast<const float4*>(z2 + j * RR + q * 4);

            f32x4 r;
            r.x = is_pair ? a.x * b.x : d0;
            r.y = is_pair ? a.y * b.y : 0.0f;
            r.z = is_pair ? a.z * b.z : 0.0f;
            r.w = is_pair ? a.w * b.w : 0.0f;

            // Streaming write (604 MB, no reuse) -> NT full-line stores
            __builtin_nontemporal_store(r, reinterpret_cast<f32x4*>(out + (size_t)idx * 4));
        }
    }
}

extern "C" void kernel_launch(void* const* d_in, const int* in_sizes, int n_in,
                              void* d_out, int out_size, void* d_ws, size_t ws_size,
                              hipStream_t stream) {
    const float* z1  = (const float*)d_in[0];
    const float* z2  = (const float*)d_in[1];
    const float* seg = (const float*)d_in[2];
    const int* cls   = (const int*)d_in[3];
    const int* batch = (const int*)d_in[4];
    float* out = (float*)d_out;
    int* key = (int*)d_ws;

    frd_key_kernel<<<(NN + 255) / 256, 256, 0, stream>>>(cls, batch, key);
    frd_main_kernel<<<BLOCKS, 256, 0, stream>>>(z1, z2, seg, key, out);
}

// Round 8
// 122.335 us; speedup vs baseline: 1.2425x; 1.2425x over previous
//
#include <hip/hip_runtime.h>
#include <cstddef>

#define NN 3072
#define RR 16
#define UNROLL 8

typedef float f32x4 __attribute__((ext_vector_type(4)));

// Prologue: key[i] = (cls not in {24,25,26}) ? batch[i] : -1
__global__ void frd_key_kernel(const int* __restrict__ cls,
                               const int* __restrict__ batch,
                               int* __restrict__ key) {
    int i = blockIdx.x * blockDim.x + threadIdx.x;
    if (i < NN) {
        int c = cls[i];
        bool valid = (c != 24) && (c != 25) && (c != 26);
        key[i] = valid ? batch[i] : -1;
    }
}

// Main: each thread handles UNROLL independent float4 quads of out [N, N, R].
// R3 structure (best: 126.6 us). This round's single change: seg loads are
// REGULAR (L2-allocating) instead of nontemporal — theory: NT loads bypass L2
// aggregation and inject scattered 64 B reads into the saturated HBM write
// stream; cached loads let L2 batch the seg stream. NT stores kept (R5: +13%).
__global__ __launch_bounds__(256)
void frd_main_kernel(const float* __restrict__ z1,
                     const float* __restrict__ z2,
                     const float* __restrict__ seg,
                     const int* __restrict__ key,
                     float* __restrict__ out) {
    const int base = blockIdx.x * (256 * UNROLL) + threadIdx.x;
    const float d0 = ((threadIdx.x & 3) == 0) ? 1.0f : 0.0f;  // one_hot(0,R) head

#pragma unroll
    for (int k = 0; k < UNROLL; ++k) {
        const int idx = base + k * 256;
        const int pair = idx >> 2;
        const int q = idx & 3;
        const int i = pair / NN;          // magic-mul by compiler
        const int j = pair - i * NN;

        // seg index == i*N + j == pair; REGULAR load (A/B vs R3's NT load)
        const float s = seg[pair];
        const int ki = key[i];            // cache-resident
        const int kj = key[j];
        // seg_eff = seg + eye; pair iff seg_eff == 0, keys match, valid
        const float seg_eff = s + ((i == j) ? 1.0f : 0.0f);
        const bool is_pair = (ki == kj) && (ki >= 0) && (seg_eff == 0.0f);

        // Unconditional loads — z1/z2 are 192 KB each, cache-resident.
        const float4 a = *reinterpret_cast<const float4*>(z1 + i * RR + q * 4);
        const float4 b = *reinterpret_cast<const float4*>(z2 + j * RR + q * 4);

        f32x4 r;
        r.x = is_pair ? a.x * b.x : d0;
        r.y = is_pair ? a.y * b.y : 0.0f;
        r.z = is_pair ? a.z * b.z : 0.0f;
        r.w = is_pair ? a.w * b.w : 0.0f;

        // Streaming write (604 MB, no reuse) -> NT full-line stores
        __builtin_nontemporal_store(r, reinterpret_cast<f32x4*>(out + (size_t)idx * 4));
    }
}

extern "C" void kernel_launch(void* const* d_in, const int* in_sizes, int n_in,
                              void* d_out, int out_size, void* d_ws, size_t ws_size,
                              hipStream_t stream) {
    const float* z1  = (const float*)d_in[0];
    const float* z2  = (const float*)d_in[1];
    const float* seg = (const float*)d_in[2];
    const int* cls   = (const int*)d_in[3];
    const int* batch = (const int*)d_in[4];
    float* out = (float*)d_out;
    int* key = (int*)d_ws;

    frd_key_kernel<<<(NN + 255) / 256, 256, 0, stream>>>(cls, batch, key);

    const int total = NN * NN * 4;          // 37,748,736 = 18,432 * 256 * 8 exactly
    frd_main_kernel<<<total / (256 * UNROLL), 256, 0, stream>>>(z1, z2, seg, key, out);
}

// Round 9
// 121.976 us; speedup vs baseline: 1.2462x; 1.0029x over previous
//
#include <hip/hip_runtime.h>
#include <cstddef>

#define NN 3072
#define RR 16
#define UNROLL 8

typedef float f32x4 __attribute__((ext_vector_type(4)));

// Prologue: key[i] = (cls not in {24,25,26}) ? batch[i] : -1
__global__ void frd_key_kernel(const int* __restrict__ cls,
                               const int* __restrict__ batch,
                               int* __restrict__ key) {
    int i = blockIdx.x * blockDim.x + threadIdx.x;
    if (i < NN) {
        int c = cls[i];
        bool valid = (c != 24) && (c != 25) && (c != 26);
        key[i] = valid ? batch[i] : -1;
    }
}

// Main: R8 structure (reg seg load, NT stores, UNROLL=8 interleaved, short
// blocks). Single change: quad mapping idx = bid*2048 + w*512 + k*64 + lane
// (was bid*2048 + k*256 + tid) -> each WAVE's 8 stores form one contiguous
// 8 KB run instead of 8 chunks at 4 KB stride. Wave-sequential HBM bursts.
__global__ __launch_bounds__(256)
void frd_main_kernel(const float* __restrict__ z1,
                     const float* __restrict__ z2,
                     const float* __restrict__ seg,
                     const int* __restrict__ key,
                     float* __restrict__ out) {
    const int tid = threadIdx.x;
    const int lane = tid & 63;
    const int w = tid >> 6;
    const int base = blockIdx.x * (256 * UNROLL) + w * (64 * UNROLL) + lane;
    const float d0 = ((lane & 3) == 0) ? 1.0f : 0.0f;  // one_hot(0,R) head

#pragma unroll
    for (int k = 0; k < UNROLL; ++k) {
        const int idx = base + k * 64;
        const int pair = idx >> 2;
        const int q = idx & 3;
        const int i = pair / NN;          // magic-mul by compiler
        const int j = pair - i * NN;

        // seg index == i*N + j == pair; regular (L2-allocating) load
        const float s = seg[pair];
        const int ki = key[i];            // cache-resident
        const int kj = key[j];
        // seg_eff = seg + eye; pair iff seg_eff == 0, keys match, valid
        const float seg_eff = s + ((i == j) ? 1.0f : 0.0f);
        const bool is_pair = (ki == kj) && (ki >= 0) && (seg_eff == 0.0f);

        // Unconditional loads — z1/z2 are 192 KB each, cache-resident.
        const float4 a = *reinterpret_cast<const float4*>(z1 + i * RR + q * 4);
        const float4 b = *reinterpret_cast<const float4*>(z2 + j * RR + q * 4);

        f32x4 r;
        r.x = is_pair ? a.x * b.x : d0;
        r.y = is_pair ? a.y * b.y : 0.0f;
        r.z = is_pair ? a.z * b.z : 0.0f;
        r.w = is_pair ? a.w * b.w : 0.0f;

        // Streaming write (604 MB, no reuse) -> NT full-line stores
        __builtin_nontemporal_store(r, reinterpret_cast<f32x4*>(out + (size_t)idx * 4));
    }
}

extern "C" void kernel_launch(void* const* d_in, const int* in_sizes, int n_in,
                              void* d_out, int out_size, void* d_ws, size_t ws_size,
                              hipStream_t stream) {
    const float* z1  = (const float*)d_in[0];
    const float* z2  = (const float*)d_in[1];
    const float* seg = (const float*)d_in[2];
    const int* cls   = (const int*)d_in[3];
    const int* batch = (const int*)d_in[4];
    float* out = (float*)d_out;
    int* key = (int*)d_ws;

    frd_key_kernel<<<(NN + 255) / 256, 256, 0, stream>>>(cls, batch, key);

    const int total = NN * NN * 4;          // 37,748,736 = 18,432 * 256 * 8 exactly
    frd_main_kernel<<<total / (256 * UNROLL), 256, 0, stream>>>(z1, z2, seg, key, out);
}